// Round 19
// baseline (322.559 us; speedup 1.0000x reference)
//
#include <hip/hip_runtime.h>

// VoxelProposalLayer — round 19: round-18 (persistent, best 296us) with P4
// split-lp pairing: (q,h,8ch-half) x {lp 0-5 | lp 6-11} across all 1024
// threads; high half stages partials in s_oa's dead triplet space; low half
// combines + stores. 16B taps, setup computed 2x (was 4x). All else identical.

typedef __attribute__((ext_vector_type(8))) short short8v;
typedef __attribute__((ext_vector_type(8))) unsigned short u16x8;
typedef __attribute__((ext_vector_type(4))) float f32x4;

#define V_TOT 262144
#define OAS 292
#define NBLK_ATTN 256

__device__ __forceinline__ unsigned short f2bf(float f) {
  unsigned int u = __float_as_uint(f);
  u += 0x7fffu + ((u >> 16) & 1u);   // RNE
  return (unsigned short)(u >> 16);
}
__device__ __forceinline__ float bf2f(unsigned short h) {
  return __uint_as_float(((unsigned int)h) << 16);
}

// ---------------- zero ----------------
__global__ void zero_kernel(unsigned int* pm) {
  pm[blockIdx.x * 512 + threadIdx.x] = 0u;   // 65536 words = 262144 B
}

__global__ void scatter_kernel(const int* __restrict__ vp, unsigned char* __restrict__ pm) {
  int v = blockIdx.x * 512 + threadIdx.x;
  int x = vp[v * 3 + 0], y = vp[v * 3 + 1], z = vp[v * 3 + 2];
  if (x >= 0 && x < 128 && y >= 0 && y < 128 && z >= 0 && z < 16)
    pm[x * 2048 + y * 16 + z] = 1;
}

// ---------------- probe: MFMA layout hypothesis + fov dtype ----------------
__global__ void probe_kernel(const unsigned char* __restrict__ fov, int* __restrict__ pflags) {
  int l = threadIdx.x;              // 64
  int n = l & 15, kb = (l >> 4) * 8;
  short8v a, b0, b17;
  #pragma unroll
  for (int e = 0; e < 8; ++e) {
    a[e]   = (short)f2bf((float)n);
    b0[e]  = (kb + e == 0)  ? (short)f2bf((float)(n + 1)) : (short)0;
    b17[e] = (kb + e == 17) ? (short)f2bf((float)(n + 3)) : (short)0;
  }
  f32x4 z = {0.f, 0.f, 0.f, 0.f};
  f32x4 d0  = __builtin_amdgcn_mfma_f32_16x16x32_bf16(a, b0,  z, 0, 0, 0);
  f32x4 d17 = __builtin_amdgcn_mfma_f32_16x16x32_bf16(a, b17, z, 0, 0, 0);
  bool ok0 = true, ok1 = true;
  #pragma unroll
  for (int r = 0; r < 4; ++r) {
    float rA = (float)((l >> 4) * 4 + r);
    float cA = (float)(l & 15);
    ok0 = ok0 && (d0[r] == rA * (cA + 1.f)) && (d17[r] == rA * (cA + 3.f));
    ok1 = ok1 && (d0[r] == cA * (rA + 1.f)) && (d17[r] == cA * (rA + 3.f));
  }
  bool all0 = __all(ok0), all1 = __all(ok1);
  if (l == 0) {
    pflags[0] = all0 ? 0 : (all1 ? 1 : 2);
    const unsigned int* fw = (const unsigned int*)fov;
    int i32mode = 1;
    for (int i = 0; i < 8; ++i) i32mode &= (fw[i] <= 1u) ? 1 : 0;
    pflags[1] = i32mode;
  }
}

// ---------------- vproj: vp_bf[s][c] = bf16(value[s]@Wv + bv) ----------------
__global__ void vproj_kernel(const float* __restrict__ f0, const float* __restrict__ f1,
                             const float* __restrict__ f2, const float* __restrict__ Wv,
                             const float* __restrict__ bv, unsigned short* __restrict__ vp) {
  __shared__ __align__(16) float lds[128][20];
  int t = threadIdx.x;            // 256
  int s0 = blockIdx.x * 16;
  const float* f; int hw, sl0;
  if (s0 < 12288)      { f = f0; hw = 12288; sl0 = s0; }
  else if (s0 < 15360) { f = f1; hw = 3072;  sl0 = s0 - 12288; }
  else                 { f = f2; hw = 768;   sl0 = s0 - 15360; }
  for (int u = 0; u < 8; ++u) {
    int idx = u * 256 + t;
    int k = idx >> 4, si = idx & 15;
    lds[k][si] = f[(size_t)k * hw + sl0 + si];
  }
  __syncthreads();
  {
    int c = t & 127, half = t >> 7;
    int base = half * 8;
    f32x4 acc0 = {0.f,0.f,0.f,0.f}, acc1 = {0.f,0.f,0.f,0.f};
    #pragma unroll 4
    for (int k = 0; k < 128; ++k) {
      float w = Wv[k * 128 + c];
      f32x4 l0 = *(const f32x4*)&lds[k][base];
      f32x4 l1 = *(const f32x4*)&lds[k][base + 4];
      acc0 += l0 * w;
      acc1 += l1 * w;
    }
    float b = bv[c];
    #pragma unroll
    for (int j = 0; j < 4; ++j) {
      vp[(size_t)(s0 + base + j)     * 128 + c] = f2bf(acc0[j] + b);
      vp[(size_t)(s0 + base + 4 + j) * 128 + c] = f2bf(acc1[j] + b);
    }
  }
}

// ---------------- wfrag: hi/lo B-fragments ----------
__global__ void wfrag_kernel(const float* __restrict__ Woff, const float* __restrict__ Wattn,
                             const float* __restrict__ Wout,
                             unsigned short* __restrict__ foa_hi, unsigned short* __restrict__ foa_lo,
                             unsigned short* __restrict__ fout_hi, unsigned short* __restrict__ fout_lo) {
  int t = blockIdx.x * 512 + threadIdx.x;     // 40960
  int e = t & 7, lane = (t >> 3) & 63, kc = (t >> 9) & 3, nt = t >> 11;
  int k = kc * 32 + (lane >> 4) * 8 + e;
  int j = nt * 16 + (lane & 15);
  float v = (j < 192) ? Woff[k * 192 + j] : ((j < 288) ? Wattn[k * 96 + (j - 192)] : 0.f);
  unsigned short hi = f2bf(v);
  foa_hi[t] = hi;
  foa_lo[t] = f2bf(v - bf2f(hi));
  if (t < 16384) {
    float w = Wout[k * 128 + j];
    unsigned short whi = f2bf(w);
    fout_hi[t] = whi;
    fout_lo[t] = f2bf(w - bf2f(whi));
  }
}

// ---------------- flagsA ----------------
__global__ __launch_bounds__(256) void flagsA_kernel(
    const unsigned char* __restrict__ pmask, const unsigned char* __restrict__ fovmask,
    const int* __restrict__ pflags, unsigned char* __restrict__ flags8,
    unsigned int* __restrict__ blkcnt) {
  __shared__ unsigned int wc[4];
  __shared__ int s_fovint;
  int t = threadIdx.x, b = blockIdx.x;
  int lane = t & 63, wid = t >> 6;
  if (t == 0) s_fovint = pflags[1];
  __syncthreads();
  int v = b * 256 + t;
  int pm = pmask[v];
  int fv = s_fovint ? ((const int*)fovmask)[v] : (int)fovmask[v];
  int fl = pm ? (fv ? 2 : 1) : 0;
  flags8[v] = (unsigned char)fl;
  unsigned long long msk = __ballot(fl == 2);
  if (lane == 0) wc[wid] = (unsigned int)__popcll(msk);
  __syncthreads();
  if (t == 0) blkcnt[b] = wc[0] + wc[1] + wc[2] + wc[3];
}

// ---------------- scan ----------------
__global__ __launch_bounds__(1024) void scan_kernel(
    const unsigned int* __restrict__ blkcnt, unsigned int* __restrict__ blkoff,
    unsigned int* __restrict__ counter) {
  __shared__ unsigned int s[1024];
  int t = threadIdx.x;
  unsigned int x = blkcnt[t];
  s[t] = x;
  __syncthreads();
  for (int off = 1; off < 1024; off <<= 1) {
    unsigned int y = (t >= off) ? s[t - off] : 0u;
    __syncthreads();
    s[t] += y;
    __syncthreads();
  }
  blkoff[t] = s[t] - x;
  if (t == 1023) *counter = s[1023];
}

// ---------------- flagsB ----------------
__global__ __launch_bounds__(256) void flagsB_kernel(
    const unsigned char* __restrict__ flags8, const unsigned int* __restrict__ blkoff,
    int* __restrict__ act, int* __restrict__ pidx) {
  __shared__ unsigned int wc[4], wo[4];
  int t = threadIdx.x, b = blockIdx.x;
  int lane = t & 63, wid = t >> 6;
  int v = b * 256 + t;
  int fl = flags8[v];
  unsigned long long msk = __ballot(fl == 2);
  if (lane == 0) wc[wid] = (unsigned int)__popcll(msk);
  __syncthreads();
  if (t == 0) {
    unsigned int s = 0;
    #pragma unroll
    for (int w = 0; w < 4; ++w) { wo[w] = s; s += wc[w]; }
  }
  __syncthreads();
  if (fl == 2) {
    int pos = (int)(blkoff[b] + wo[wid]) + __popcll(msk & ((1ull << lane) - 1ull));
    act[pos] = v;
    pidx[v] = pos;
  }
}

// ---------------- writer ----------------
__global__ __launch_bounds__(256) void writer_kernel(
    const float* __restrict__ embed, const unsigned char* __restrict__ flags8,
    const int* __restrict__ pidx, const float* __restrict__ abuf, int mode_buf,
    float* __restrict__ out) {
  __shared__ float tr[64][133];
  __shared__ int sfl[64];
  __shared__ int spx[64];
  int t = threadIdx.x;
  int v0 = blockIdx.x * 64;
  if (t < 64) {
    int fl = flags8[v0 + t];
    sfl[t] = fl;
    spx[t] = (fl == 2) ? pidx[v0 + t] : -1;
  }
  __syncthreads();
  #pragma unroll
  for (int rep = 0; rep < 8; ++rep) {
    int idx = rep * 256 + t;            // 2048 f4 tasks: 64 rows x 32
    int i = idx >> 5, c4 = idx & 31;
    int fl = sfl[i];
    float4 val = {0.f, 0.f, 0.f, 0.f};
    if (mode_buf && fl == 2)
      val = *(const float4*)&abuf[(size_t)spx[i] * 128 + c4 * 4];
    else if (fl == 0)
      val = *(const float4*)&embed[(size_t)(v0 + i) * 128 + c4 * 4];
    tr[i][c4 * 4 + 0] = val.x;
    tr[i][c4 * 4 + 1] = val.y;
    tr[i][c4 * 4 + 2] = val.z;
    tr[i][c4 * 4 + 3] = val.w;
  }
  __syncthreads();
  float4* out4 = (float4*)out;
  #pragma unroll
  for (int rep = 0; rep < 8; ++rep) {
    int task = rep * 256 + t;           // 2048: 128 c x 16 f4-groups
    int c = task >> 4, g = task & 15;
    float4 o;
    o.x = tr[g * 4 + 0][c];
    o.y = tr[g * 4 + 1][c];
    o.z = tr[g * 4 + 2][c];
    o.w = tr[g * 4 + 3][c];
    out4[(size_t)c * (V_TOT / 4) + (v0 >> 2) + g] = o;
  }
}

// ---------------- main attention kernel (32-q tiles, 1024 thr, persistent) --
__global__ __launch_bounds__(1024, 4) void attn_kernel(
    const float* __restrict__ embed, const float* __restrict__ pos,
    const float* __restrict__ refp, const unsigned short* __restrict__ vproj,
    const unsigned short* __restrict__ WfragOAh, const unsigned short* __restrict__ WfragOAl,
    const unsigned short* __restrict__ WfragOuth, const unsigned short* __restrict__ WfragOutl,
    const float* __restrict__ boff, const float* __restrict__ battn,
    const float* __restrict__ bout, const float* __restrict__ lng, const float* __restrict__ lnb,
    const int* __restrict__ act, const unsigned int* __restrict__ counter,
    const int* __restrict__ pflags, float* __restrict__ abuf, int dstmode,
    float* __restrict__ out) {
  __shared__ __align__(16) float s_oa[32 * OAS];
  __shared__ __align__(16) unsigned short s_qhi[32 * 128];
  __shared__ __align__(16) unsigned short s_qlo[32 * 128];
  __shared__ int s_vidx[32];
  __shared__ float s_reff[64];
  __shared__ float s_boff[192], s_battn[96], s_bout[128], s_lng[128], s_lnb[128];
  __shared__ int s_meta[3];

  int t = threadIdx.x;
  int wid = t >> 6, lane = t & 63;

  if (t == 0) {
    int cnt = (int)*counter;
    s_meta[0] = cnt;
    s_meta[1] = pflags[0];
    s_meta[2] = (cnt + 31) >> 5;
  }
  if (t < 192) s_boff[t]  = boff[t];
  if (t < 96)  s_battn[t] = battn[t];
  if (t < 128) { s_bout[t] = bout[t]; s_lng[t] = lng[t]; s_lnb[t] = lnb[t]; }
  __syncthreads();
  int count = s_meta[0], mflag = s_meta[1], ntiles = s_meta[2];

  for (int tile = blockIdx.x; tile < ntiles; tile += NBLK_ATTN) {
    int q0 = tile * 32;
    // ---- P0 ----
    if (t < 32) s_vidx[t] = (q0 + t < count) ? act[q0 + t] : -1;
    if (t < 64) {
      int i = t >> 1, comp = t & 1;
      int idx = q0 + i;
      int vid = (idx < count) ? act[idx] : -1;
      s_reff[t] = (vid >= 0) ? refp[(size_t)vid * 2 + comp] : 0.f;
    }
    {
      int fi = t;                         // 1024 f4 (32 rows x 32)
      int i = fi >> 5, c4 = fi & 31;
      int idx = q0 + i;
      int vid = (idx < count) ? act[idx] : -1;
      ushort4 hk = {0,0,0,0}, lk = {0,0,0,0};
      if (vid >= 0) {
        float4 ev = *(const float4*)(embed + (size_t)vid * 128 + c4 * 4);
        float4 pv = *(const float4*)(pos   + (size_t)vid * 128 + c4 * 4);
        float q_0 = ev.x + pv.x, q_1 = ev.y + pv.y, q_2 = ev.z + pv.z, q_3 = ev.w + pv.w;
        hk.x = f2bf(q_0); lk.x = f2bf(q_0 - bf2f(hk.x));
        hk.y = f2bf(q_1); lk.y = f2bf(q_1 - bf2f(hk.y));
        hk.z = f2bf(q_2); lk.z = f2bf(q_2 - bf2f(hk.z));
        hk.w = f2bf(q_3); lk.w = f2bf(q_3 - bf2f(hk.w));
      }
      int c = c4 * 4;
      int idxl = i * 128 + (((c >> 3) ^ (i & 7)) << 3) + (c & 7);
      *(ushort4*)&s_qhi[idxl] = hk;
      *(ushort4*)&s_qlo[idxl] = lk;
    }
    __syncthreads();

    // ---- P1: q @ [Woff|Wattn]; 40 wave-tasks (2 mrow x 20 nt), 1 acc each ----
    {
      #pragma unroll 1
      for (int tk = wid; tk < 40; tk += 16) {
        int mrow = (tk >= 20) ? 16 : 0;
        int nt = (tk >= 20) ? (tk - 20) : tk;
        f32x4 acc = (f32x4){0.f,0.f,0.f,0.f};
        int arow = mrow + (lane & 15);
        int asub = lane >> 4;
        #pragma unroll 1
        for (int kc = 0; kc < 4; ++kc) {
          int slot = kc * 4 + asub;
          int aidx = arow * 128 + ((slot ^ (arow & 7)) << 3);
          short8v ah = *(const short8v*)&s_qhi[aidx];
          short8v al = *(const short8v*)&s_qlo[aidx];
          size_t bi = (size_t)((nt * 4 + kc) * 64 + lane) * 8;
          short8v bh = *(const short8v*)&WfragOAh[bi];
          short8v bl = *(const short8v*)&WfragOAl[bi];
          acc = __builtin_amdgcn_mfma_f32_16x16x32_bf16(ah, bh, acc, 0, 0, 0);
          acc = __builtin_amdgcn_mfma_f32_16x16x32_bf16(al, bh, acc, 0, 0, 0);
          acc = __builtin_amdgcn_mfma_f32_16x16x32_bf16(ah, bl, acc, 0, 0, 0);
        }
        #pragma unroll
        for (int e = 0; e < 4; ++e) {
          int rr = (mflag == 0) ? ((lane >> 4) * 4 + e) : (lane & 15);
          int cc = (mflag == 0) ? (lane & 15) : ((lane >> 4) * 4 + e);
          int col = nt * 16 + cc;
          if (col < 288) s_oa[(mrow + rr) * OAS + col] = acc[e];
        }
      }
    }
    __syncthreads();

    // ---- P2: softmax over 12 per (query,head); 256 tasks ----
    if (t < 256) {
      int i = t >> 3, h = t & 7;
      float* p = &s_oa[i * OAS + 192 + h * 12];
      const float* bb = &s_battn[h * 12];
      float l[12];
      float m = -1e30f;
      #pragma unroll
      for (int j = 0; j < 12; ++j) { l[j] = p[j] + bb[j]; m = fmaxf(m, l[j]); }
      float sum = 0.f;
      #pragma unroll
      for (int j = 0; j < 12; ++j) { l[j] = __expf(l[j] - m); sum += l[j]; }
      float inv = 1.0f / sum;
      #pragma unroll
      for (int j = 0; j < 12; ++j) p[j] = l[j] * inv;
    }
    __syncthreads();

    // ---- P3: rewrite as (locx,locy,aw) triplets; 3072 tasks ----
    {
      const float invWn[3] = {1.f/192.f, 1.f/96.f, 1.f/48.f};
      const float invHn[3] = {1.f/64.f, 1.f/32.f, 1.f/16.f};
      float st[3][3];
      #pragma unroll
      for (int u = 0; u < 3; ++u) {
        int task = u * 1024 + t;
        int i = task / 96, s = task % 96;
        int h = s / 12, lp = s % 12, l = lp >> 2, p = lp & 3;
        int oidx = ((h * 3 + l) * 4 + p) * 2;
        float ox = s_oa[i * OAS + oidx] + s_boff[oidx];
        float oy = s_oa[i * OAS + oidx + 1] + s_boff[oidx + 1];
        float aw = s_oa[i * OAS + 192 + h * 12 + lp];
        st[u][0] = s_reff[i * 2] + ox * invWn[l];
        st[u][1] = s_reff[i * 2 + 1] + oy * invHn[l];
        st[u][2] = aw;
      }
      __syncthreads();
      #pragma unroll
      for (int u = 0; u < 3; ++u) {
        int task = u * 1024 + t;
        int i = task / 96, s = task % 96;
        float* d = &s_oa[i * OAS + s * 3];
        d[0] = st[u][0]; d[1] = st[u][1]; d[2] = st[u][2];
      }
    }
    __syncthreads();

    // ---- P4: pair-split sampling. tid=(q,h,8ch-half) over 512; lg=t>>9
    //      lg=0 -> lp 0..5, lg=1 -> lp 6..11; partials staged in s_oa. ----
    {
      int tid = t & 511, lg = t >> 9;
      int i = tid >> 4, h = (tid & 15) >> 1, half = tid & 1;
      int dh0 = half * 8;
      float acc[8];
      #pragma unroll
      for (int e = 0; e < 8; ++e) acc[e] = 0.f;
      if (s_vidx[i] >= 0) {
        #pragma unroll 1
        for (int sub = 0; sub < 6; ++sub) {
          int lp = lg * 6 + sub;
          int l = lp >> 2;
          int Wl = 192 >> l, Hl = 64 >> l;
          int Bl = (l == 0) ? 0 : ((l == 1) ? 12288 : 15360);
          const float* pd = &s_oa[i * OAS + (h * 12 + lp) * 3];
          float lx = pd[0], ly = pd[1], aw = pd[2];
          float x = lx * (float)Wl - 0.5f, y = ly * (float)Hl - 0.5f;
          float xf = floorf(x), yf = floorf(y);
          float wx = x - xf, wy = y - yf;
          int x0 = (int)xf, y0 = (int)yf;
          int x1 = x0 + 1, y1 = y0 + 1;
          int x0c = min(max(x0, 0), Wl - 1), x1c = min(max(x1, 0), Wl - 1);
          int y0c = min(max(y0, 0), Hl - 1), y1c = min(max(y1, 0), Hl - 1);
          float vx0 = (x0 >= 0 && x0 < Wl) ? 1.f : 0.f;
          float vx1 = (x1 >= 0 && x1 < Wl) ? 1.f : 0.f;
          float vy0 = (y0 >= 0 && y0 < Hl) ? 1.f : 0.f;
          float vy1 = (y1 >= 0 && y1 < Hl) ? 1.f : 0.f;
          const unsigned short* vb = vproj + (size_t)Bl * 128 + h * 16 + dh0;
          u16x8 t00 = *(const u16x8*)(vb + (size_t)(y0c * Wl + x0c) * 128);
          u16x8 t01 = *(const u16x8*)(vb + (size_t)(y0c * Wl + x1c) * 128);
          u16x8 t10 = *(const u16x8*)(vb + (size_t)(y1c * Wl + x0c) * 128);
          u16x8 t11 = *(const u16x8*)(vb + (size_t)(y1c * Wl + x1c) * 128);
          float w00 = (1.f - wx) * (1.f - wy) * vx0 * vy0;
          float w01 = wx * (1.f - wy) * vx1 * vy0;
          float w10 = (1.f - wx) * wy * vx0 * vy1;
          float w11 = wx * wy * vx1 * vy1;
          #pragma unroll
          for (int e = 0; e < 8; ++e) {
            float sv = w00 * bf2f(t00[e]) + w01 * bf2f(t01[e])
                     + w10 * bf2f(t10[e]) + w11 * bf2f(t11[e]);
            acc[e] += aw * sv;
          }
        }
      }
      __syncthreads();     // all triplet reads complete
      if (lg == 1) {       // stage high-half partials in dead triplet space
        float* dst = &s_oa[i * OAS + (h * 2 + half) * 8];
        #pragma unroll
        for (int e = 0; e < 8; ++e) dst[e] = acc[e];
      }
      __syncthreads();
      if (lg == 0) {       // combine + convert + swizzled store
        const float* src = &s_oa[i * OAS + (h * 2 + half) * 8];
        int c = h * 16 + dh0;             // c&7 == 0
        int idxl = i * 128 + (((c >> 3) ^ (i & 7)) << 3);
        short8v hk, lk;
        #pragma unroll
        for (int e = 0; e < 8; ++e) {
          float v = acc[e] + src[e];
          unsigned short hi = f2bf(v);
          hk[e] = (short)hi;
          lk[e] = (short)f2bf(v - bf2f(hi));
        }
        *(short8v*)&s_qhi[idxl] = hk;
        *(short8v*)&s_qlo[idxl] = lk;
      }
    }
    __syncthreads();

    // ---- P5: acc @ Wout; 16 wave-tasks (2 mrow x 8 nt), 1 acc each ----
    {
      int mrow = (wid & 1) * 16;
      int nt = wid >> 1;                    // 0..7
      f32x4 acc2 = (f32x4){0.f,0.f,0.f,0.f};
      int arow = mrow + (lane & 15);
      int asub = lane >> 4;
      #pragma unroll 1
      for (int kc = 0; kc < 4; ++kc) {
        int slot = kc * 4 + asub;
        int aidx = arow * 128 + ((slot ^ (arow & 7)) << 3);
        short8v ah = *(const short8v*)&s_qhi[aidx];
        short8v al = *(const short8v*)&s_qlo[aidx];
        size_t bi = (size_t)((nt * 4 + kc) * 64 + lane) * 8;
        short8v bh = *(const short8v*)&WfragOuth[bi];
        short8v bl = *(const short8v*)&WfragOutl[bi];
        acc2 = __builtin_amdgcn_mfma_f32_16x16x32_bf16(ah, bh, acc2, 0, 0, 0);
        acc2 = __builtin_amdgcn_mfma_f32_16x16x32_bf16(al, bh, acc2, 0, 0, 0);
        acc2 = __builtin_amdgcn_mfma_f32_16x16x32_bf16(ah, bl, acc2, 0, 0, 0);
      }
      #pragma unroll
      for (int e = 0; e < 4; ++e) {
        int rr = (mflag == 0) ? ((lane >> 4) * 4 + e) : (lane & 15);
        int cc = (mflag == 0) ? (lane & 15) : ((lane >> 4) * 4 + e);
        int row = mrow + rr;
        int col = nt * 16 + cc;
        int vid = s_vidx[row];
        float idv = (vid >= 0) ? embed[(size_t)vid * 128 + col] : 0.f;
        s_oa[row * OAS + col] = acc2[e] + idv + s_bout[col];
      }
    }
    __syncthreads();

    // ---- P6: LayerNorm rows; 512 tasks ----
    if (t < 512) {
      int i = t >> 4, j = t & 15;
      float* rowp = &s_oa[i * OAS];
      float4 a = *(float4*)&rowp[j * 8];
      float4 b = *(float4*)&rowp[j * 8 + 4];
      float vals[8] = {a.x, a.y, a.z, a.w, b.x, b.y, b.z, b.w};
      float sum = 0.f, sq = 0.f;
      #pragma unroll
      for (int e = 0; e < 8; ++e) { sum += vals[e]; sq += vals[e] * vals[e]; }
      #pragma unroll
      for (int m = 1; m < 16; m <<= 1) {
        sum += __shfl_xor(sum, m);
        sq  += __shfl_xor(sq, m);
      }
      float mean = sum * (1.f / 128.f);
      float var = sq * (1.f / 128.f) - mean * mean;
      float rs = rsqrtf(var + 1e-5f);
      #pragma unroll
      for (int e = 0; e < 8; ++e) {
        int c = j * 8 + e;
        rowp[c] = (vals[e] - mean) * rs * s_lng[c] + s_lnb[c];
      }
    }
    __syncthreads();

    // ---- P7 ----
    if (dstmode) {
      int i = t >> 5, c4 = t & 31;        // 1024 f4: 32 rows x 32
      if (s_vidx[i] >= 0) {
        float4 o;
        o.x = s_oa[i * OAS + c4 * 4 + 0];
        o.y = s_oa[i * OAS + c4 * 4 + 1];
        o.z = s_oa[i * OAS + c4 * 4 + 2];
        o.w = s_oa[i * OAS + c4 * 4 + 3];
        *(float4*)&abuf[(size_t)(q0 + i) * 128 + c4 * 4] = o;
      }
    } else {
      #pragma unroll
      for (int rep = 0; rep < 4; ++rep) {
        int idx = rep * 1024 + t;         // 4096: 128 c x 32 q
        int c = idx >> 5, i = idx & 31;
        int vid = s_vidx[i];
        if (vid >= 0) out[(size_t)c * V_TOT + vid] = s_oa[i * OAS + c];
      }
    }
    __syncthreads();
  }
}

extern "C" void kernel_launch(void* const* d_in, const int* in_sizes, int n_in,
                              void* d_out, int out_size, void* d_ws, size_t ws_size,
                              hipStream_t stream) {
  const float* embed = (const float*)d_in[0];
  const float* pos   = (const float*)d_in[1];
  const float* refp  = (const float*)d_in[2];
  const float* f0    = (const float*)d_in[3];
  const float* f1    = (const float*)d_in[4];
  const float* f2    = (const float*)d_in[5];
  const float* Wv    = (const float*)d_in[6];
  const float* bv    = (const float*)d_in[7];
  const float* Woff  = (const float*)d_in[8];
  const float* boff  = (const float*)d_in[9];
  const float* Wattn = (const float*)d_in[10];
  const float* battn = (const float*)d_in[11];
  const float* Wout  = (const float*)d_in[12];
  const float* bout  = (const float*)d_in[13];
  const float* lng   = (const float*)d_in[14];
  const float* lnb   = (const float*)d_in[15];
  const int*   volp  = (const int*)d_in[16];
  const unsigned char* fov = (const unsigned char*)d_in[17];
  float* out = (float*)d_out;

  char* ws = (char*)d_ws;
  unsigned short* vproj  = (unsigned short*)(ws + 0);            // 4,128,768
  unsigned char*  pmask  = (unsigned char*)(ws + 4128768);       // 262,144
  unsigned int*   counter= (unsigned int*)(ws + 4390912);        // 128
  int*            pflags = (int*)(ws + 4391040);                 // 128
  unsigned short* foa_hi = (unsigned short*)(ws + 4391168);      // 81,920
  unsigned short* foa_lo = (unsigned short*)(ws + 4473088);      // 81,920
  unsigned short* fout_hi= (unsigned short*)(ws + 4555008);      // 32,768
  unsigned short* fout_lo= (unsigned short*)(ws + 4587776);      // 32,768
  int*            act    = (int*)(ws + 4833536);                 // 1,048,576
  unsigned char*  flags8 = (unsigned char*)(ws + 5882112);       // 262,144
  int*            pidx   = (int*)(ws + 6144256);                 // 1,048,576
  unsigned int*   blkcnt = (unsigned int*)(ws + 7192832);        // 4,096
  unsigned int*   blkoff = (unsigned int*)(ws + 7196928);        // 4,096
  float*          abuf   = (float*)(ws + 7201024);               // up to 134,217,728

  int use_buf = (ws_size >= (size_t)7201024 + (size_t)134217728) ? 1 : 0;

  zero_kernel<<<128, 512, 0, stream>>>((unsigned int*)pmask);
  scatter_kernel<<<512, 512, 0, stream>>>(volp, pmask);
  probe_kernel<<<1, 64, 0, stream>>>(fov, pflags);
  vproj_kernel<<<1008, 256, 0, stream>>>(f0, f1, f2, Wv, bv, vproj);
  wfrag_kernel<<<80, 512, 0, stream>>>(Woff, Wattn, Wout, foa_hi, foa_lo,
                                       fout_hi, fout_lo);
  flagsA_kernel<<<1024, 256, 0, stream>>>(pmask, fov, pflags, flags8, blkcnt);
  scan_kernel<<<1, 1024, 0, stream>>>(blkcnt, blkoff, counter);
  flagsB_kernel<<<1024, 256, 0, stream>>>(flags8, blkoff, act, pidx);

  if (use_buf) {
    attn_kernel<<<NBLK_ATTN, 1024, 0, stream>>>(embed, pos, refp, vproj,
                                                foa_hi, foa_lo, fout_hi, fout_lo,
                                                boff, battn, bout, lng, lnb,
                                                act, counter, pflags, abuf, 1, out);
    writer_kernel<<<4096, 256, 0, stream>>>(embed, flags8, pidx, abuf, 1, out);
  } else {
    writer_kernel<<<4096, 256, 0, stream>>>(embed, flags8, pidx, abuf, 0, out);
    attn_kernel<<<NBLK_ATTN, 1024, 0, stream>>>(embed, pos, refp, vproj,
                                                foa_hi, foa_lo, fout_hi, fout_lo,
                                                boff, battn, bout, lng, lnb,
                                                act, counter, pflags, abuf, 0, out);
  }
}

// Round 20
// 291.380 us; speedup vs baseline: 1.1070x; 1.1070x over previous
//
#include <hip/hip_runtime.h>

// VoxelProposalLayer — round 20: REVERT to verified round-18 optimum
// (total 296us, attn 219us). Round-19's lp-pair-split refuted: +90MB FETCH
// (locality loss), +20MB WRITE, VALUBusy 47->32. This config is the measured
// best under the three confirmed HW walls (1 WG/CU, 64 VGPR @1024thr,
// tap locality).

typedef __attribute__((ext_vector_type(8))) short short8v;
typedef __attribute__((ext_vector_type(4))) float f32x4;

#define V_TOT 262144
#define OAS 292
#define NBLK_ATTN 256

__device__ __forceinline__ unsigned short f2bf(float f) {
  unsigned int u = __float_as_uint(f);
  u += 0x7fffu + ((u >> 16) & 1u);   // RNE
  return (unsigned short)(u >> 16);
}
__device__ __forceinline__ float bf2f(unsigned short h) {
  return __uint_as_float(((unsigned int)h) << 16);
}

// ---------------- zero ----------------
__global__ void zero_kernel(unsigned int* pm) {
  pm[blockIdx.x * 512 + threadIdx.x] = 0u;   // 65536 words = 262144 B
}

__global__ void scatter_kernel(const int* __restrict__ vp, unsigned char* __restrict__ pm) {
  int v = blockIdx.x * 512 + threadIdx.x;
  int x = vp[v * 3 + 0], y = vp[v * 3 + 1], z = vp[v * 3 + 2];
  if (x >= 0 && x < 128 && y >= 0 && y < 128 && z >= 0 && z < 16)
    pm[x * 2048 + y * 16 + z] = 1;
}

// ---------------- probe: MFMA layout hypothesis + fov dtype ----------------
__global__ void probe_kernel(const unsigned char* __restrict__ fov, int* __restrict__ pflags) {
  int l = threadIdx.x;              // 64
  int n = l & 15, kb = (l >> 4) * 8;
  short8v a, b0, b17;
  #pragma unroll
  for (int e = 0; e < 8; ++e) {
    a[e]   = (short)f2bf((float)n);
    b0[e]  = (kb + e == 0)  ? (short)f2bf((float)(n + 1)) : (short)0;
    b17[e] = (kb + e == 17) ? (short)f2bf((float)(n + 3)) : (short)0;
  }
  f32x4 z = {0.f, 0.f, 0.f, 0.f};
  f32x4 d0  = __builtin_amdgcn_mfma_f32_16x16x32_bf16(a, b0,  z, 0, 0, 0);
  f32x4 d17 = __builtin_amdgcn_mfma_f32_16x16x32_bf16(a, b17, z, 0, 0, 0);
  bool ok0 = true, ok1 = true;
  #pragma unroll
  for (int r = 0; r < 4; ++r) {
    float rA = (float)((l >> 4) * 4 + r);
    float cA = (float)(l & 15);
    ok0 = ok0 && (d0[r] == rA * (cA + 1.f)) && (d17[r] == rA * (cA + 3.f));
    ok1 = ok1 && (d0[r] == cA * (rA + 1.f)) && (d17[r] == cA * (rA + 3.f));
  }
  bool all0 = __all(ok0), all1 = __all(ok1);
  if (l == 0) {
    pflags[0] = all0 ? 0 : (all1 ? 1 : 2);
    const unsigned int* fw = (const unsigned int*)fov;
    int i32mode = 1;
    for (int i = 0; i < 8; ++i) i32mode &= (fw[i] <= 1u) ? 1 : 0;
    pflags[1] = i32mode;
  }
}

// ---------------- vproj: vp_bf[s][c] = bf16(value[s]@Wv + bv) ----------------
__global__ void vproj_kernel(const float* __restrict__ f0, const float* __restrict__ f1,
                             const float* __restrict__ f2, const float* __restrict__ Wv,
                             const float* __restrict__ bv, unsigned short* __restrict__ vp) {
  __shared__ __align__(16) float lds[128][20];
  int t = threadIdx.x;            // 256
  int s0 = blockIdx.x * 16;
  const float* f; int hw, sl0;
  if (s0 < 12288)      { f = f0; hw = 12288; sl0 = s0; }
  else if (s0 < 15360) { f = f1; hw = 3072;  sl0 = s0 - 12288; }
  else                 { f = f2; hw = 768;   sl0 = s0 - 15360; }
  for (int u = 0; u < 8; ++u) {
    int idx = u * 256 + t;
    int k = idx >> 4, si = idx & 15;
    lds[k][si] = f[(size_t)k * hw + sl0 + si];
  }
  __syncthreads();
  {
    int c = t & 127, half = t >> 7;
    int base = half * 8;
    f32x4 acc0 = {0.f,0.f,0.f,0.f}, acc1 = {0.f,0.f,0.f,0.f};
    #pragma unroll 4
    for (int k = 0; k < 128; ++k) {
      float w = Wv[k * 128 + c];
      f32x4 l0 = *(const f32x4*)&lds[k][base];
      f32x4 l1 = *(const f32x4*)&lds[k][base + 4];
      acc0 += l0 * w;
      acc1 += l1 * w;
    }
    float b = bv[c];
    #pragma unroll
    for (int j = 0; j < 4; ++j) {
      vp[(size_t)(s0 + base + j)     * 128 + c] = f2bf(acc0[j] + b);
      vp[(size_t)(s0 + base + 4 + j) * 128 + c] = f2bf(acc1[j] + b);
    }
  }
}

// ---------------- wfrag: hi/lo B-fragments ----------
__global__ void wfrag_kernel(const float* __restrict__ Woff, const float* __restrict__ Wattn,
                             const float* __restrict__ Wout,
                             unsigned short* __restrict__ foa_hi, unsigned short* __restrict__ foa_lo,
                             unsigned short* __restrict__ fout_hi, unsigned short* __restrict__ fout_lo) {
  int t = blockIdx.x * 512 + threadIdx.x;     // 40960
  int e = t & 7, lane = (t >> 3) & 63, kc = (t >> 9) & 3, nt = t >> 11;
  int k = kc * 32 + (lane >> 4) * 8 + e;
  int j = nt * 16 + (lane & 15);
  float v = (j < 192) ? Woff[k * 192 + j] : ((j < 288) ? Wattn[k * 96 + (j - 192)] : 0.f);
  unsigned short hi = f2bf(v);
  foa_hi[t] = hi;
  foa_lo[t] = f2bf(v - bf2f(hi));
  if (t < 16384) {
    float w = Wout[k * 128 + j];
    unsigned short whi = f2bf(w);
    fout_hi[t] = whi;
    fout_lo[t] = f2bf(w - bf2f(whi));
  }
}

// ---------------- flagsA ----------------
__global__ __launch_bounds__(256) void flagsA_kernel(
    const unsigned char* __restrict__ pmask, const unsigned char* __restrict__ fovmask,
    const int* __restrict__ pflags, unsigned char* __restrict__ flags8,
    unsigned int* __restrict__ blkcnt) {
  __shared__ unsigned int wc[4];
  __shared__ int s_fovint;
  int t = threadIdx.x, b = blockIdx.x;
  int lane = t & 63, wid = t >> 6;
  if (t == 0) s_fovint = pflags[1];
  __syncthreads();
  int v = b * 256 + t;
  int pm = pmask[v];
  int fv = s_fovint ? ((const int*)fovmask)[v] : (int)fovmask[v];
  int fl = pm ? (fv ? 2 : 1) : 0;
  flags8[v] = (unsigned char)fl;
  unsigned long long msk = __ballot(fl == 2);
  if (lane == 0) wc[wid] = (unsigned int)__popcll(msk);
  __syncthreads();
  if (t == 0) blkcnt[b] = wc[0] + wc[1] + wc[2] + wc[3];
}

// ---------------- scan ----------------
__global__ __launch_bounds__(1024) void scan_kernel(
    const unsigned int* __restrict__ blkcnt, unsigned int* __restrict__ blkoff,
    unsigned int* __restrict__ counter) {
  __shared__ unsigned int s[1024];
  int t = threadIdx.x;
  unsigned int x = blkcnt[t];
  s[t] = x;
  __syncthreads();
  for (int off = 1; off < 1024; off <<= 1) {
    unsigned int y = (t >= off) ? s[t - off] : 0u;
    __syncthreads();
    s[t] += y;
    __syncthreads();
  }
  blkoff[t] = s[t] - x;
  if (t == 1023) *counter = s[1023];
}

// ---------------- flagsB ----------------
__global__ __launch_bounds__(256) void flagsB_kernel(
    const unsigned char* __restrict__ flags8, const unsigned int* __restrict__ blkoff,
    int* __restrict__ act, int* __restrict__ pidx) {
  __shared__ unsigned int wc[4], wo[4];
  int t = threadIdx.x, b = blockIdx.x;
  int lane = t & 63, wid = t >> 6;
  int v = b * 256 + t;
  int fl = flags8[v];
  unsigned long long msk = __ballot(fl == 2);
  if (lane == 0) wc[wid] = (unsigned int)__popcll(msk);
  __syncthreads();
  if (t == 0) {
    unsigned int s = 0;
    #pragma unroll
    for (int w = 0; w < 4; ++w) { wo[w] = s; s += wc[w]; }
  }
  __syncthreads();
  if (fl == 2) {
    int pos = (int)(blkoff[b] + wo[wid]) + __popcll(msk & ((1ull << lane) - 1ull));
    act[pos] = v;
    pidx[v] = pos;
  }
}

// ---------------- writer ----------------
__global__ __launch_bounds__(256) void writer_kernel(
    const float* __restrict__ embed, const unsigned char* __restrict__ flags8,
    const int* __restrict__ pidx, const float* __restrict__ abuf, int mode_buf,
    float* __restrict__ out) {
  __shared__ float tr[64][133];
  __shared__ int sfl[64];
  __shared__ int spx[64];
  int t = threadIdx.x;
  int v0 = blockIdx.x * 64;
  if (t < 64) {
    int fl = flags8[v0 + t];
    sfl[t] = fl;
    spx[t] = (fl == 2) ? pidx[v0 + t] : -1;
  }
  __syncthreads();
  #pragma unroll
  for (int rep = 0; rep < 8; ++rep) {
    int idx = rep * 256 + t;            // 2048 f4 tasks: 64 rows x 32
    int i = idx >> 5, c4 = idx & 31;
    int fl = sfl[i];
    float4 val = {0.f, 0.f, 0.f, 0.f};
    if (mode_buf && fl == 2)
      val = *(const float4*)&abuf[(size_t)spx[i] * 128 + c4 * 4];
    else if (fl == 0)
      val = *(const float4*)&embed[(size_t)(v0 + i) * 128 + c4 * 4];
    tr[i][c4 * 4 + 0] = val.x;
    tr[i][c4 * 4 + 1] = val.y;
    tr[i][c4 * 4 + 2] = val.z;
    tr[i][c4 * 4 + 3] = val.w;
  }
  __syncthreads();
  float4* out4 = (float4*)out;
  #pragma unroll
  for (int rep = 0; rep < 8; ++rep) {
    int task = rep * 256 + t;           // 2048: 128 c x 16 f4-groups
    int c = task >> 4, g = task & 15;
    float4 o;
    o.x = tr[g * 4 + 0][c];
    o.y = tr[g * 4 + 1][c];
    o.z = tr[g * 4 + 2][c];
    o.w = tr[g * 4 + 3][c];
    out4[(size_t)c * (V_TOT / 4) + (v0 >> 2) + g] = o;
  }
}

// ---------------- main attention kernel (32-q tiles, 1024 thr, persistent) --
__global__ __launch_bounds__(1024, 4) void attn_kernel(
    const float* __restrict__ embed, const float* __restrict__ pos,
    const float* __restrict__ refp, const unsigned short* __restrict__ vproj,
    const unsigned short* __restrict__ WfragOAh, const unsigned short* __restrict__ WfragOAl,
    const unsigned short* __restrict__ WfragOuth, const unsigned short* __restrict__ WfragOutl,
    const float* __restrict__ boff, const float* __restrict__ battn,
    const float* __restrict__ bout, const float* __restrict__ lng, const float* __restrict__ lnb,
    const int* __restrict__ act, const unsigned int* __restrict__ counter,
    const int* __restrict__ pflags, float* __restrict__ abuf, int dstmode,
    float* __restrict__ out) {
  __shared__ __align__(16) float s_oa[32 * OAS];
  __shared__ __align__(16) unsigned short s_qhi[32 * 128];
  __shared__ __align__(16) unsigned short s_qlo[32 * 128];
  __shared__ int s_vidx[32];
  __shared__ float s_reff[64];
  __shared__ float s_boff[192], s_battn[96], s_bout[128], s_lng[128], s_lnb[128];
  __shared__ int s_meta[3];

  int t = threadIdx.x;
  int wid = t >> 6, lane = t & 63;

  if (t == 0) {
    int cnt = (int)*counter;
    s_meta[0] = cnt;
    s_meta[1] = pflags[0];
    s_meta[2] = (cnt + 31) >> 5;
  }
  if (t < 192) s_boff[t]  = boff[t];
  if (t < 96)  s_battn[t] = battn[t];
  if (t < 128) { s_bout[t] = bout[t]; s_lng[t] = lng[t]; s_lnb[t] = lnb[t]; }
  __syncthreads();
  int count = s_meta[0], mflag = s_meta[1], ntiles = s_meta[2];

  for (int tile = blockIdx.x; tile < ntiles; tile += NBLK_ATTN) {
    int q0 = tile * 32;
    // ---- P0 ----
    if (t < 32) s_vidx[t] = (q0 + t < count) ? act[q0 + t] : -1;
    if (t < 64) {
      int i = t >> 1, comp = t & 1;
      int idx = q0 + i;
      int vid = (idx < count) ? act[idx] : -1;
      s_reff[t] = (vid >= 0) ? refp[(size_t)vid * 2 + comp] : 0.f;
    }
    {
      int fi = t;                         // 1024 f4 (32 rows x 32)
      int i = fi >> 5, c4 = fi & 31;
      int idx = q0 + i;
      int vid = (idx < count) ? act[idx] : -1;
      ushort4 hk = {0,0,0,0}, lk = {0,0,0,0};
      if (vid >= 0) {
        float4 ev = *(const float4*)(embed + (size_t)vid * 128 + c4 * 4);
        float4 pv = *(const float4*)(pos   + (size_t)vid * 128 + c4 * 4);
        float q_0 = ev.x + pv.x, q_1 = ev.y + pv.y, q_2 = ev.z + pv.z, q_3 = ev.w + pv.w;
        hk.x = f2bf(q_0); lk.x = f2bf(q_0 - bf2f(hk.x));
        hk.y = f2bf(q_1); lk.y = f2bf(q_1 - bf2f(hk.y));
        hk.z = f2bf(q_2); lk.z = f2bf(q_2 - bf2f(hk.z));
        hk.w = f2bf(q_3); lk.w = f2bf(q_3 - bf2f(hk.w));
      }
      int c = c4 * 4;
      int idxl = i * 128 + (((c >> 3) ^ (i & 7)) << 3) + (c & 7);
      *(ushort4*)&s_qhi[idxl] = hk;
      *(ushort4*)&s_qlo[idxl] = lk;
    }
    __syncthreads();

    // ---- P1: q @ [Woff|Wattn]; 40 wave-tasks (2 mrow x 20 nt), 1 acc each ----
    {
      #pragma unroll 1
      for (int tk = wid; tk < 40; tk += 16) {
        int mrow = (tk >= 20) ? 16 : 0;
        int nt = (tk >= 20) ? (tk - 20) : tk;
        f32x4 acc = (f32x4){0.f,0.f,0.f,0.f};
        int arow = mrow + (lane & 15);
        int asub = lane >> 4;
        #pragma unroll 1
        for (int kc = 0; kc < 4; ++kc) {
          int slot = kc * 4 + asub;
          int aidx = arow * 128 + ((slot ^ (arow & 7)) << 3);
          short8v ah = *(const short8v*)&s_qhi[aidx];
          short8v al = *(const short8v*)&s_qlo[aidx];
          size_t bi = (size_t)((nt * 4 + kc) * 64 + lane) * 8;
          short8v bh = *(const short8v*)&WfragOAh[bi];
          short8v bl = *(const short8v*)&WfragOAl[bi];
          acc = __builtin_amdgcn_mfma_f32_16x16x32_bf16(ah, bh, acc, 0, 0, 0);
          acc = __builtin_amdgcn_mfma_f32_16x16x32_bf16(al, bh, acc, 0, 0, 0);
          acc = __builtin_amdgcn_mfma_f32_16x16x32_bf16(ah, bl, acc, 0, 0, 0);
        }
        #pragma unroll
        for (int e = 0; e < 4; ++e) {
          int rr = (mflag == 0) ? ((lane >> 4) * 4 + e) : (lane & 15);
          int cc = (mflag == 0) ? (lane & 15) : ((lane >> 4) * 4 + e);
          int col = nt * 16 + cc;
          if (col < 288) s_oa[(mrow + rr) * OAS + col] = acc[e];
        }
      }
    }
    __syncthreads();

    // ---- P2: softmax over 12 per (query,head); 256 tasks ----
    if (t < 256) {
      int i = t >> 3, h = t & 7;
      float* p = &s_oa[i * OAS + 192 + h * 12];
      const float* bb = &s_battn[h * 12];
      float l[12];
      float m = -1e30f;
      #pragma unroll
      for (int j = 0; j < 12; ++j) { l[j] = p[j] + bb[j]; m = fmaxf(m, l[j]); }
      float sum = 0.f;
      #pragma unroll
      for (int j = 0; j < 12; ++j) { l[j] = __expf(l[j] - m); sum += l[j]; }
      float inv = 1.0f / sum;
      #pragma unroll
      for (int j = 0; j < 12; ++j) p[j] = l[j] * inv;
    }
    __syncthreads();

    // ---- P3: rewrite as (locx,locy,aw) triplets; 3072 tasks ----
    {
      const float invWn[3] = {1.f/192.f, 1.f/96.f, 1.f/48.f};
      const float invHn[3] = {1.f/64.f, 1.f/32.f, 1.f/16.f};
      float st[3][3];
      #pragma unroll
      for (int u = 0; u < 3; ++u) {
        int task = u * 1024 + t;
        int i = task / 96, s = task % 96;
        int h = s / 12, lp = s % 12, l = lp >> 2, p = lp & 3;
        int oidx = ((h * 3 + l) * 4 + p) * 2;
        float ox = s_oa[i * OAS + oidx] + s_boff[oidx];
        float oy = s_oa[i * OAS + oidx + 1] + s_boff[oidx + 1];
        float aw = s_oa[i * OAS + 192 + h * 12 + lp];
        st[u][0] = s_reff[i * 2] + ox * invWn[l];
        st[u][1] = s_reff[i * 2 + 1] + oy * invHn[l];
        st[u][2] = aw;
      }
      __syncthreads();
      #pragma unroll
      for (int u = 0; u < 3; ++u) {
        int task = u * 1024 + t;
        int i = task / 96, s = task % 96;
        float* d = &s_oa[i * OAS + s * 3];
        d[0] = st[u][0]; d[1] = st[u][1]; d[2] = st[u][2];
      }
    }
    __syncthreads();

    // ---- P4: thread = (query, head, 4ch-quarter); 1024 tasks, 8B taps ----
    {
      int i = t >> 5, h = (t >> 2) & 7, q4 = t & 3;
      int dh0 = q4 * 4;
      float acc[4];
      #pragma unroll
      for (int e = 0; e < 4; ++e) acc[e] = 0.f;
      if (s_vidx[i] >= 0) {
        #pragma unroll 2
        for (int lp = 0; lp < 12; ++lp) {
          const int Wl = (lp < 4) ? 192 : ((lp < 8) ? 96 : 48);
          const int Hl = (lp < 4) ? 64 : ((lp < 8) ? 32 : 16);
          const int Bl = (lp < 4) ? 0 : ((lp < 8) ? 12288 : 15360);
          const float* pd = &s_oa[i * OAS + (h * 12 + lp) * 3];
          float lx = pd[0], ly = pd[1], aw = pd[2];
          float x = lx * (float)Wl - 0.5f, y = ly * (float)Hl - 0.5f;
          float xf = floorf(x), yf = floorf(y);
          float wx = x - xf, wy = y - yf;
          int x0 = (int)xf, y0 = (int)yf;
          int x1 = x0 + 1, y1 = y0 + 1;
          int x0c = min(max(x0, 0), Wl - 1), x1c = min(max(x1, 0), Wl - 1);
          int y0c = min(max(y0, 0), Hl - 1), y1c = min(max(y1, 0), Hl - 1);
          float vx0 = (x0 >= 0 && x0 < Wl) ? 1.f : 0.f;
          float vx1 = (x1 >= 0 && x1 < Wl) ? 1.f : 0.f;
          float vy0 = (y0 >= 0 && y0 < Hl) ? 1.f : 0.f;
          float vy1 = (y1 >= 0 && y1 < Hl) ? 1.f : 0.f;
          const unsigned short* vb = vproj + (size_t)Bl * 128 + h * 16 + dh0;
          ushort4 t00 = *(const ushort4*)(vb + (size_t)(y0c * Wl + x0c) * 128);
          ushort4 t01 = *(const ushort4*)(vb + (size_t)(y0c * Wl + x1c) * 128);
          ushort4 t10 = *(const ushort4*)(vb + (size_t)(y1c * Wl + x0c) * 128);
          ushort4 t11 = *(const ushort4*)(vb + (size_t)(y1c * Wl + x1c) * 128);
          float w00 = (1.f - wx) * (1.f - wy) * vx0 * vy0;
          float w01 = wx * (1.f - wy) * vx1 * vy0;
          float w10 = (1.f - wx) * wy * vx0 * vy1;
          float w11 = wx * wy * vx1 * vy1;
          const unsigned short* p00 = (const unsigned short*)&t00;
          const unsigned short* p01 = (const unsigned short*)&t01;
          const unsigned short* p10 = (const unsigned short*)&t10;
          const unsigned short* p11 = (const unsigned short*)&t11;
          #pragma unroll
          for (int e = 0; e < 4; ++e) {
            float sv = w00 * bf2f(p00[e]) + w01 * bf2f(p01[e])
                     + w10 * bf2f(p10[e]) + w11 * bf2f(p11[e]);
            acc[e] += aw * sv;
          }
        }
      }
      int c = h * 16 + dh0;                 // c&7 in {0,4}
      int idxl = i * 128 + (((c >> 3) ^ (i & 7)) << 3) + (c & 7);
      ushort4 hk, lk;
      unsigned short* hp = (unsigned short*)&hk;
      unsigned short* lp2 = (unsigned short*)&lk;
      #pragma unroll
      for (int e = 0; e < 4; ++e) {
        unsigned short hi = f2bf(acc[e]);
        hp[e] = hi;
        lp2[e] = f2bf(acc[e] - bf2f(hi));
      }
      *(ushort4*)&s_qhi[idxl] = hk;
      *(ushort4*)&s_qlo[idxl] = lk;
    }
    __syncthreads();

    // ---- P5: acc @ Wout; 16 wave-tasks (2 mrow x 8 nt), 1 acc each ----
    {
      int mrow = (wid & 1) * 16;
      int nt = wid >> 1;                    // 0..7
      f32x4 acc2 = (f32x4){0.f,0.f,0.f,0.f};
      int arow = mrow + (lane & 15);
      int asub = lane >> 4;
      #pragma unroll 1
      for (int kc = 0; kc < 4; ++kc) {
        int slot = kc * 4 + asub;
        int aidx = arow * 128 + ((slot ^ (arow & 7)) << 3);
        short8v ah = *(const short8v*)&s_qhi[aidx];
        short8v al = *(const short8v*)&s_qlo[aidx];
        size_t bi = (size_t)((nt * 4 + kc) * 64 + lane) * 8;
        short8v bh = *(const short8v*)&WfragOuth[bi];
        short8v bl = *(const short8v*)&WfragOutl[bi];
        acc2 = __builtin_amdgcn_mfma_f32_16x16x32_bf16(ah, bh, acc2, 0, 0, 0);
        acc2 = __builtin_amdgcn_mfma_f32_16x16x32_bf16(al, bh, acc2, 0, 0, 0);
        acc2 = __builtin_amdgcn_mfma_f32_16x16x32_bf16(ah, bl, acc2, 0, 0, 0);
      }
      #pragma unroll
      for (int e = 0; e < 4; ++e) {
        int rr = (mflag == 0) ? ((lane >> 4) * 4 + e) : (lane & 15);
        int cc = (mflag == 0) ? (lane & 15) : ((lane >> 4) * 4 + e);
        int row = mrow + rr;
        int col = nt * 16 + cc;
        int vid = s_vidx[row];
        float idv = (vid >= 0) ? embed[(size_t)vid * 128 + col] : 0.f;
        s_oa[row * OAS + col] = acc2[e] + idv + s_bout[col];
      }
    }
    __syncthreads();

    // ---- P6: LayerNorm rows; 512 tasks ----
    if (t < 512) {
      int i = t >> 4, j = t & 15;
      float* rowp = &s_oa[i * OAS];
      float4 a = *(float4*)&rowp[j * 8];
      float4 b = *(float4*)&rowp[j * 8 + 4];
      float vals[8] = {a.x, a.y, a.z, a.w, b.x, b.y, b.z, b.w};
      float sum = 0.f, sq = 0.f;
      #pragma unroll
      for (int e = 0; e < 8; ++e) { sum += vals[e]; sq += vals[e] * vals[e]; }
      #pragma unroll
      for (int m = 1; m < 16; m <<= 1) {
        sum += __shfl_xor(sum, m);
        sq  += __shfl_xor(sq, m);
      }
      float mean = sum * (1.f / 128.f);
      float var = sq * (1.f / 128.f) - mean * mean;
      float rs = rsqrtf(var + 1e-5f);
      #pragma unroll
      for (int e = 0; e < 8; ++e) {
        int c = j * 8 + e;
        rowp[c] = (vals[e] - mean) * rs * s_lng[c] + s_lnb[c];
      }
    }
    __syncthreads();

    // ---- P7 ----
    if (dstmode) {
      int i = t >> 5, c4 = t & 31;        // 1024 f4: 32 rows x 32
      if (s_vidx[i] >= 0) {
        float4 o;
        o.x = s_oa[i * OAS + c4 * 4 + 0];
        o.y = s_oa[i * OAS + c4 * 4 + 1];
        o.z = s_oa[i * OAS + c4 * 4 + 2];
        o.w = s_oa[i * OAS + c4 * 4 + 3];
        *(float4*)&abuf[(size_t)(q0 + i) * 128 + c4 * 4] = o;
      }
    } else {
      #pragma unroll
      for (int rep = 0; rep < 4; ++rep) {
        int idx = rep * 1024 + t;         // 4096: 128 c x 32 q
        int c = idx >> 5, i = idx & 31;
        int vid = s_vidx[i];
        if (vid >= 0) out[(size_t)c * V_TOT + vid] = s_oa[i * OAS + c];
      }
    }
    __syncthreads();
  }
}

extern "C" void kernel_launch(void* const* d_in, const int* in_sizes, int n_in,
                              void* d_out, int out_size, void* d_ws, size_t ws_size,
                              hipStream_t stream) {
  const float* embed = (const float*)d_in[0];
  const float* pos   = (const float*)d_in[1];
  const float* refp  = (const float*)d_in[2];
  const float* f0    = (const float*)d_in[3];
  const float* f1    = (const float*)d_in[4];
  const float* f2    = (const float*)d_in[5];
  const float* Wv    = (const float*)d_in[6];
  const float* bv    = (const float*)d_in[7];
  const float* Woff  = (const float*)d_in[8];
  const float* boff  = (const float*)d_in[9];
  const float* Wattn = (const float*)d_in[10];
  const float* battn = (const float*)d_in[11];
  const float* Wout  = (const float*)d_in[12];
  const float* bout  = (const float*)d_in[13];
  const float* lng   = (const float*)d_in[14];
  const float* lnb   = (const float*)d_in[15];
  const int*   volp  = (const int*)d_in[16];
  const unsigned char* fov = (const unsigned char*)d_in[17];
  float* out = (float*)d_out;

  char* ws = (char*)d_ws;
  unsigned short* vproj  = (unsigned short*)(ws + 0);            // 4,128,768
  unsigned char*  pmask  = (unsigned char*)(ws + 4128768);       // 262,144
  unsigned int*   counter= (unsigned int*)(ws + 4390912);        // 128
  int*            pflags = (int*)(ws + 4391040);                 // 128
  unsigned short* foa_hi = (unsigned short*)(ws + 4391168);      // 81,920
  unsigned short* foa_lo = (unsigned short*)(ws + 4473088);      // 81,920
  unsigned short* fout_hi= (unsigned short*)(ws + 4555008);      // 32,768
  unsigned short* fout_lo= (unsigned short*)(ws + 4587776);      // 32,768
  int*            act    = (int*)(ws + 4833536);                 // 1,048,576
  unsigned char*  flags8 = (unsigned char*)(ws + 5882112);       // 262,144
  int*            pidx   = (int*)(ws + 6144256);                 // 1,048,576
  unsigned int*   blkcnt = (unsigned int*)(ws + 7192832);        // 4,096
  unsigned int*   blkoff = (unsigned int*)(ws + 7196928);        // 4,096
  float*          abuf   = (float*)(ws + 7201024);               // up to 134,217,728

  int use_buf = (ws_size >= (size_t)7201024 + (size_t)134217728) ? 1 : 0;

  zero_kernel<<<128, 512, 0, stream>>>((unsigned int*)pmask);
  scatter_kernel<<<512, 512, 0, stream>>>(volp, pmask);
  probe_kernel<<<1, 64, 0, stream>>>(fov, pflags);
  vproj_kernel<<<1008, 256, 0, stream>>>(f0, f1, f2, Wv, bv, vproj);
  wfrag_kernel<<<80, 512, 0, stream>>>(Woff, Wattn, Wout, foa_hi, foa_lo,
                                       fout_hi, fout_lo);
  flagsA_kernel<<<1024, 256, 0, stream>>>(pmask, fov, pflags, flags8, blkcnt);
  scan_kernel<<<1, 1024, 0, stream>>>(blkcnt, blkoff, counter);
  flagsB_kernel<<<1024, 256, 0, stream>>>(flags8, blkoff, act, pidx);

  if (use_buf) {
    attn_kernel<<<NBLK_ATTN, 1024, 0, stream>>>(embed, pos, refp, vproj,
                                                foa_hi, foa_lo, fout_hi, fout_lo,
                                                boff, battn, bout, lng, lnb,
                                                act, counter, pflags, abuf, 1, out);
    writer_kernel<<<4096, 256, 0, stream>>>(embed, flags8, pidx, abuf, 1, out);
  } else {
    writer_kernel<<<4096, 256, 0, stream>>>(embed, flags8, pidx, abuf, 0, out);
    attn_kernel<<<NBLK_ATTN, 1024, 0, stream>>>(embed, pos, refp, vproj,
                                                foa_hi, foa_lo, fout_hi, fout_lo,
                                                boff, battn, bout, lng, lnb,
                                                act, counter, pflags, abuf, 0, out);
  }
}